// Round 1
// baseline (2372.678 us; speedup 1.0000x reference)
//
#include <hip/hip_runtime.h>

#define IN_F  4096
#define OUT_F 4096
#define BW    512
#define BM    128
#define BN    128
#define BK    32

// Offset of row o's first element in W_values (prefix sum of band row counts).
// counts[o] = o+513 (o<512), 1025 (512<=o<=3583), 4608-o (o>=3584)
__device__ __forceinline__ int band_start(int o) {
    if (o <= 512)  return o * 513 + ((o * (o - 1)) >> 1);
    if (o <= 3584) return 393472 + (o - 512) * 1025;
    const int d = o - 3584;
    return 3542272 + (((1024 + (4609 - o)) * d) >> 1);
}

__global__ __launch_bounds__(256) void band_gemm_f32(
    const float* __restrict__ x,
    const float* __restrict__ wv,
    const float* __restrict__ bias,
    float* __restrict__ out,
    int M)
{
    __shared__ float Xs[BM][BK + 1];   // [m][k], pad 1 -> broadcast reads conflict-free
    __shared__ float Ws[BK][BN + 2];   // [k][o], pad 2 -> float2 reads 8B-aligned, <=2-way

    const int tid  = threadIdx.x;
    const int tx   = tid & 15;   // o-dim micro-tile
    const int ty   = tid >> 4;   // m-dim micro-tile
    const int bcol = blockIdx.x * BN;
    const int brow = blockIdx.y * BM;

    const int klo = (bcol >= BW) ? (bcol - BW) : 0;        // multiple of 128
    const int khi = min(IN_F, bcol + BN + BW);             // multiple of 128

    float acc[8][8];
    #pragma unroll
    for (int a = 0; a < 8; ++a)
        #pragma unroll
        for (int b = 0; b < 8; ++b) acc[a][b] = 0.f;

    // X-load geometry: float4 per thread, 32 rows/pass
    const int xc4 = (tid & 7) * 4;
    const int xr0 = tid >> 3;          // 0..31
    // W-load geometry: scalar along i (contiguous in W_values within a row)
    const int wc  = tid & 31;          // k offset 0..31
    const int wr0 = tid >> 5;          // o offset base 0..7

    for (int k0 = klo; k0 < khi; k0 += BK) {
        // ---- stage X tile [128][32]
        #pragma unroll
        for (int p = 0; p < 4; ++p) {
            const int r = xr0 + 32 * p;
            const float4 v = *reinterpret_cast<const float4*>(
                &x[(size_t)(brow + r) * IN_F + (k0 + xc4)]);
            Xs[r][xc4 + 0] = v.x;
            Xs[r][xc4 + 1] = v.y;
            Xs[r][xc4 + 2] = v.z;
            Xs[r][xc4 + 3] = v.w;
        }
        // ---- stage W tile [32][128] (k-major), zero outside band
        const int i = k0 + wc;
        #pragma unroll
        for (int p = 0; p < 16; ++p) {
            const int r = wr0 + 8 * p;
            const int o = bcol + r;
            const int lo = (o >= BW) ? (o - BW) : 0;
            float v = 0.f;
            if (i >= o - BW && i <= o + BW)
                v = wv[band_start(o) + (i - lo)];
            Ws[wc][r] = v;
        }
        __syncthreads();

        // ---- 8x8 register tile FMA
        #pragma unroll
        for (int k = 0; k < BK; ++k) {
            float am[8];
            #pragma unroll
            for (int a = 0; a < 8; ++a) am[a] = Xs[ty * 8 + a][k];
            float bo[8];
            const float2 q0 = *reinterpret_cast<const float2*>(&Ws[k][tx * 4]);
            const float2 q1 = *reinterpret_cast<const float2*>(&Ws[k][tx * 4 + 2]);
            const float2 q2 = *reinterpret_cast<const float2*>(&Ws[k][tx * 4 + 64]);
            const float2 q3 = *reinterpret_cast<const float2*>(&Ws[k][tx * 4 + 66]);
            bo[0] = q0.x; bo[1] = q0.y; bo[2] = q1.x; bo[3] = q1.y;
            bo[4] = q2.x; bo[5] = q2.y; bo[6] = q3.x; bo[7] = q3.y;
            #pragma unroll
            for (int a = 0; a < 8; ++a)
                #pragma unroll
                for (int b = 0; b < 8; ++b)
                    acc[a][b] = fmaf(am[a], bo[b], acc[a][b]);
        }
        __syncthreads();
    }

    // ---- epilogue: bias + coalesced float4 stores
    float bs[8];
    #pragma unroll
    for (int b = 0; b < 4; ++b) bs[b]     = bias[bcol + tx * 4 + b];
    #pragma unroll
    for (int b = 0; b < 4; ++b) bs[4 + b] = bias[bcol + tx * 4 + 64 + b];

    #pragma unroll
    for (int a = 0; a < 8; ++a) {
        const size_t row = (size_t)(brow + ty * 8 + a);
        const float4 v0 = make_float4(acc[a][0] + bs[0], acc[a][1] + bs[1],
                                      acc[a][2] + bs[2], acc[a][3] + bs[3]);
        const float4 v1 = make_float4(acc[a][4] + bs[4], acc[a][5] + bs[5],
                                      acc[a][6] + bs[6], acc[a][7] + bs[7]);
        *reinterpret_cast<float4*>(&out[row * OUT_F + bcol + tx * 4])      = v0;
        *reinterpret_cast<float4*>(&out[row * OUT_F + bcol + tx * 4 + 64]) = v1;
    }
}

extern "C" void kernel_launch(void* const* d_in, const int* in_sizes, int n_in,
                              void* d_out, int out_size, void* d_ws, size_t ws_size,
                              hipStream_t stream) {
    const float* x    = (const float*)d_in[0];
    const float* wv   = (const float*)d_in[1];
    const float* bias = (const float*)d_in[2];
    float* out        = (float*)d_out;

    const int M = in_sizes[0] / IN_F;          // 8192
    dim3 grid(OUT_F / BN, M / BM);             // (32, 64)
    band_gemm_f32<<<grid, 256, 0, stream>>>(x, wv, bias, out, M);
}

// Round 2
// 189.760 us; speedup vs baseline: 12.5036x; 12.5036x over previous
//
#include <hip/hip_runtime.h>
#include <stdint.h>

#define IN_F  4096
#define OUT_F 4096
#define BW    512
#define WB    1152   // padded k-window per 128-col tile: [bcol-512, bcol+640)
#define BM    128
#define BN    128
#define BK    32

typedef __bf16 bf16x8 __attribute__((ext_vector_type(8)));
typedef float  f32x4  __attribute__((ext_vector_type(4)));

// Offset of row o's first element in W_values (prefix sum of band row counts).
__device__ __forceinline__ int band_start(int o) {
    if (o <= 512)  return o * 513 + ((o * (o - 1)) >> 1);
    if (o <= 3584) return 393472 + (o - 512) * 1025;
    const int d = o - 3584;
    return 3542272 + (((1024 + 4609 - o) * d) >> 1);
}

__device__ __forceinline__ uint16_t f32_to_bf16(float f) {
    uint32_t u = __builtin_bit_cast(uint32_t, f);
    u += 0x7FFFu + ((u >> 16) & 1u);   // RNE
    return (uint16_t)(u >> 16);
}

// ---- pass 1: x fp32 -> bf16 dense [M][4096]
__global__ __launch_bounds__(256) void cvt_x(const float* __restrict__ x,
                                             uint16_t* __restrict__ xb, int n4) {
    const int stride = gridDim.x * 256;
    for (int i = blockIdx.x * 256 + threadIdx.x; i < n4; i += stride) {
        const float4 v = reinterpret_cast<const float4*>(x)[i];
        const uint32_t lo = (uint32_t)f32_to_bf16(v.x) | ((uint32_t)f32_to_bf16(v.y) << 16);
        const uint32_t hi = (uint32_t)f32_to_bf16(v.z) | ((uint32_t)f32_to_bf16(v.w) << 16);
        reinterpret_cast<uint2*>(xb)[i] = make_uint2(lo, hi);
    }
}

// ---- pass 2: densify band -> Wd[o][j] bf16, j indexes k = (o&~127)-512+j, zero outside band
__global__ __launch_bounds__(128) void cvt_w(const float* __restrict__ wv,
                                             uint16_t* __restrict__ wd) {
    const int o = blockIdx.y;
    const int j = blockIdx.x * 128 + threadIdx.x;     // 0..1151
    const int i = (o & ~(BM - 1)) - BW + j;
    uint16_t v = 0;
    if (i >= o - BW && i <= o + BW && i >= 0 && i < IN_F) {
        const int lo = (o > BW) ? (o - BW) : 0;
        v = f32_to_bf16(wv[band_start(o) + (i - lo)]);
    }
    wd[o * WB + j] = v;
}

// ---- pass 3: bf16 MFMA GEMM over the band window (m97 structure)
__global__ __launch_bounds__(256) void band_gemm_bf16(
    const uint16_t* __restrict__ xb,
    const uint16_t* __restrict__ wd,
    const float* __restrict__ bias,
    float* __restrict__ out)
{
    __shared__ __align__(128) uint8_t lds[16384];     // A: [0,8K) B: [8K,16K)

    // XCD-aware bijective swizzle (nwg = 2048, %8 == 0)
    const int id = blockIdx.x;
    const int cpx = gridDim.x >> 3;
    const int wg = (id & 7) * cpx + (id >> 3);
    const int bx = wg & 31;                  // N tile 0..31
    const int by = wg >> 5;                  // M tile
    const int brow = by * BM;
    const int bcol = bx * BN;

    const int wlo = bcol - BW;                                  // window start (may be <0)
    const int kstart = wlo > 0 ? wlo : 0;                       // multiple of 128
    const int kend = (bcol + BN + BW) < IN_F ? (bcol + BN + BW) : IN_F;

    const int tid = threadIdx.x;
    const int w    = tid >> 6;
    const int lane = tid & 63;
    const int ln = lane & 15;
    const int kc = lane >> 4;

    // staging: linear LDS dest (global_load_lds), inverse-swizzled global source.
    // tile layout: byte t stores logical (r = t>>6, chunk c = ((t>>4)&3) ^ ((r>>1)&3))
    const int t0 = (w << 10) | (lane << 4);
    const int r0 = t0 >> 6;                  // 0..63 (call h=1 adds 64; (r>>1)&3 unchanged)
    const int cc = ((t0 >> 4) & 3) ^ ((r0 >> 1) & 3);

    const uint16_t* srcA0 = xb + (size_t)(brow + r0) * IN_F + kstart + cc * 8;
    const uint16_t* srcA1 = srcA0 + (size_t)64 * IN_F;
    const uint16_t* srcB0 = wd + (size_t)(bcol + r0) * WB + (kstart - wlo) + cc * 8;
    const uint16_t* srcB1 = srcB0 + (size_t)64 * WB;

    uint8_t* ldsA = &lds[0]    + (w << 10);
    uint8_t* ldsB = &lds[8192] + (w << 10);

    // compute: wave (w>>1, w&1) owns 64x64; fragment reads use the same swizzle
    const int mbase = (w >> 1) << 6;
    const int obase = (w & 1) << 6;
    const int swz = (kc ^ ((ln >> 1) & 3)) << 4;
    const uint8_t* pA = &lds[0]    + ((mbase + ln) << 6) + swz;   // + a*1024
    const uint8_t* pB = &lds[8192] + ((obase + ln) << 6) + swz;   // + b*1024

    f32x4 acc[4][4] = {};

    for (int k0 = kstart; k0 < kend; k0 += BK) {
        __builtin_amdgcn_global_load_lds((const __attribute__((address_space(1))) uint32_t*)srcA0,
                                         (__attribute__((address_space(3))) uint32_t*)ldsA, 16, 0, 0);
        __builtin_amdgcn_global_load_lds((const __attribute__((address_space(1))) uint32_t*)srcA1,
                                         (__attribute__((address_space(3))) uint32_t*)(ldsA + 4096), 16, 0, 0);
        __builtin_amdgcn_global_load_lds((const __attribute__((address_space(1))) uint32_t*)srcB0,
                                         (__attribute__((address_space(3))) uint32_t*)ldsB, 16, 0, 0);
        __builtin_amdgcn_global_load_lds((const __attribute__((address_space(1))) uint32_t*)srcB1,
                                         (__attribute__((address_space(3))) uint32_t*)(ldsB + 4096), 16, 0, 0);
        srcA0 += BK; srcA1 += BK; srcB0 += BK; srcB1 += BK;
        __syncthreads();   // drains vmcnt(0) before s_barrier -> staged data visible

        bf16x8 af[4], bfr[4];
        #pragma unroll
        for (int a = 0; a < 4; ++a)
            af[a] = *reinterpret_cast<const bf16x8*>(pA + a * 1024);
        #pragma unroll
        for (int b = 0; b < 4; ++b)
            bfr[b] = *reinterpret_cast<const bf16x8*>(pB + b * 1024);
        #pragma unroll
        for (int a = 0; a < 4; ++a)
            #pragma unroll
            for (int b = 0; b < 4; ++b)
                acc[a][b] = __builtin_amdgcn_mfma_f32_16x16x32_bf16(af[a], bfr[b], acc[a][b], 0, 0, 0);
        __syncthreads();
    }

    // epilogue: C/D map col = lane&15, row = (lane>>4)*4 + q
    float bsv[4];
    #pragma unroll
    for (int b = 0; b < 4; ++b) bsv[b] = bias[bcol + obase + b * 16 + ln];

    #pragma unroll
    for (int a = 0; a < 4; ++a) {
        #pragma unroll
        for (int q = 0; q < 4; ++q) {
            const int row = brow + mbase + a * 16 + (kc << 2) + q;
            float* po = out + (size_t)row * OUT_F + bcol + obase + ln;
            #pragma unroll
            for (int b = 0; b < 4; ++b)
                po[b * 16] = acc[a][b][q] + bsv[b];
        }
    }
}

// ---- fallback (ws too small): round-1 fp32 kernel, known correct
__global__ __launch_bounds__(256) void band_gemm_f32(
    const float* __restrict__ x, const float* __restrict__ wv,
    const float* __restrict__ bias, float* __restrict__ out, int M)
{
    __shared__ float Xs[BM][BK + 1];
    __shared__ float Ws[BK][BN + 2];
    const int tid = threadIdx.x;
    const int tx = tid & 15, ty = tid >> 4;
    const int bcol = blockIdx.x * BN, brow = blockIdx.y * BM;
    const int klo = (bcol >= BW) ? (bcol - BW) : 0;
    const int khi = min(IN_F, bcol + BN + BW);
    float acc[8][8];
    #pragma unroll
    for (int a = 0; a < 8; ++a)
        #pragma unroll
        for (int b = 0; b < 8; ++b) acc[a][b] = 0.f;
    const int xc4 = (tid & 7) * 4, xr0 = tid >> 3;
    const int wc = tid & 31, wr0 = tid >> 5;
    for (int k0 = klo; k0 < khi; k0 += BK) {
        #pragma unroll
        for (int p = 0; p < 4; ++p) {
            const int r = xr0 + 32 * p;
            const float4 v = *reinterpret_cast<const float4*>(&x[(size_t)(brow + r) * IN_F + (k0 + xc4)]);
            Xs[r][xc4 + 0] = v.x; Xs[r][xc4 + 1] = v.y; Xs[r][xc4 + 2] = v.z; Xs[r][xc4 + 3] = v.w;
        }
        const int i = k0 + wc;
        #pragma unroll
        for (int p = 0; p < 16; ++p) {
            const int r = wr0 + 8 * p;
            const int o = bcol + r;
            const int lo = (o >= BW) ? (o - BW) : 0;
            float v = 0.f;
            if (i >= o - BW && i <= o + BW) v = wv[band_start(o) + (i - lo)];
            Ws[wc][r] = v;
        }
        __syncthreads();
        #pragma unroll
        for (int k = 0; k < BK; ++k) {
            float am[8];
            #pragma unroll
            for (int a = 0; a < 8; ++a) am[a] = Xs[ty * 8 + a][k];
            float bo[8];
            const float2 q0 = *reinterpret_cast<const float2*>(&Ws[k][tx * 4]);
            const float2 q1 = *reinterpret_cast<const float2*>(&Ws[k][tx * 4 + 2]);
            const float2 q2 = *reinterpret_cast<const float2*>(&Ws[k][tx * 4 + 64]);
            const float2 q3 = *reinterpret_cast<const float2*>(&Ws[k][tx * 4 + 66]);
            bo[0] = q0.x; bo[1] = q0.y; bo[2] = q1.x; bo[3] = q1.y;
            bo[4] = q2.x; bo[5] = q2.y; bo[6] = q3.x; bo[7] = q3.y;
            #pragma unroll
            for (int a = 0; a < 8; ++a)
                #pragma unroll
                for (int b = 0; b < 8; ++b) acc[a][b] = fmaf(am[a], bo[b], acc[a][b]);
        }
        __syncthreads();
    }
    float bs[8];
    #pragma unroll
    for (int b = 0; b < 4; ++b) bs[b] = bias[bcol + tx * 4 + b];
    #pragma unroll
    for (int b = 0; b < 4; ++b) bs[4 + b] = bias[bcol + tx * 4 + 64 + b];
    #pragma unroll
    for (int a = 0; a < 8; ++a) {
        const size_t row = (size_t)(brow + ty * 8 + a);
        const float4 v0 = make_float4(acc[a][0] + bs[0], acc[a][1] + bs[1], acc[a][2] + bs[2], acc[a][3] + bs[3]);
        const float4 v1 = make_float4(acc[a][4] + bs[4], acc[a][5] + bs[5], acc[a][6] + bs[6], acc[a][7] + bs[7]);
        *reinterpret_cast<float4*>(&out[row * OUT_F + bcol + tx * 4]) = v0;
        *reinterpret_cast<float4*>(&out[row * OUT_F + bcol + tx * 4 + 64]) = v1;
    }
}

extern "C" void kernel_launch(void* const* d_in, const int* in_sizes, int n_in,
                              void* d_out, int out_size, void* d_ws, size_t ws_size,
                              hipStream_t stream) {
    const float* x    = (const float*)d_in[0];
    const float* wv   = (const float*)d_in[1];
    const float* bias = (const float*)d_in[2];
    float* out        = (float*)d_out;

    const int M = in_sizes[0] / IN_F;                         // 8192
    const size_t xb_bytes = (size_t)M * IN_F * 2;             // 64 MB
    const size_t wd_bytes = (size_t)OUT_F * WB * 2;           // 9.4 MB

    if (ws_size >= xb_bytes + wd_bytes && (M % BM) == 0) {
        uint16_t* xb = (uint16_t*)d_ws;
        uint16_t* wdp = (uint16_t*)((uint8_t*)d_ws + xb_bytes);
        cvt_x<<<2048, 256, 0, stream>>>(x, xb, M * IN_F / 4);
        cvt_w<<<dim3(WB / 128, OUT_F), 128, 0, stream>>>(wv, wdp);
        band_gemm_bf16<<<(M / BM) * (OUT_F / BN), 256, 0, stream>>>(xb, wdp, bias, out);
    } else {
        dim3 grid(OUT_F / BN, M / BM);
        band_gemm_f32<<<grid, 256, 0, stream>>>(x, wv, bias, out, M);
    }
}

// Round 3
// 150.918 us; speedup vs baseline: 15.7216x; 1.2574x over previous
//
#include <hip/hip_runtime.h>
#include <stdint.h>

#define IN_F  4096
#define OUT_F 4096
#define BW    512
#define BM    256
#define BN    256
#define BK    32
#define WB2   1280   // padded k-window per 256-col tile: [bcol-512, bcol+768)

typedef __bf16 bf16x8 __attribute__((ext_vector_type(8)));
typedef float  f32x4  __attribute__((ext_vector_type(4)));

__device__ __forceinline__ int band_start(int o) {
    if (o <= 512)  return o * 513 + ((o * (o - 1)) >> 1);
    if (o <= 3584) return 393472 + (o - 512) * 1025;
    const int d = o - 3584;
    return 3542272 + (((1024 + 4609 - o) * d) >> 1);
}

__device__ __forceinline__ uint16_t f32_to_bf16(float f) {
    uint32_t u = __builtin_bit_cast(uint32_t, f);
    u += 0x7FFFu + ((u >> 16) & 1u);   // RNE
    return (uint16_t)(u >> 16);
}

// ---- pass 1: x fp32 -> bf16 dense [M][4096]
__global__ __launch_bounds__(256) void cvt_x(const float* __restrict__ x,
                                             uint16_t* __restrict__ xb, int n4) {
    const int stride = gridDim.x * 256;
    for (int i = blockIdx.x * 256 + threadIdx.x; i < n4; i += stride) {
        const float4 v = reinterpret_cast<const float4*>(x)[i];
        const uint32_t lo = (uint32_t)f32_to_bf16(v.x) | ((uint32_t)f32_to_bf16(v.y) << 16);
        const uint32_t hi = (uint32_t)f32_to_bf16(v.z) | ((uint32_t)f32_to_bf16(v.w) << 16);
        reinterpret_cast<uint2*>(xb)[i] = make_uint2(lo, hi);
    }
}

// ---- pass 2: densify band -> wd[o][j], j indexes k = (o&~255)-512+j, zero outside band
__global__ __launch_bounds__(256) void cvt_w(const float* __restrict__ wv,
                                             uint16_t* __restrict__ wd) {
    const int o = blockIdx.y;
    const int j = blockIdx.x * 256 + threadIdx.x;     // 0..1279
    const int i = (o & ~(BM - 1)) - BW + j;
    uint16_t v = 0;
    if (i >= o - BW && i <= o + BW && i >= 0 && i < IN_F) {
        const int lo = (o > BW) ? (o - BW) : 0;
        v = f32_to_bf16(wv[band_start(o) + (i - lo)]);
    }
    wd[o * WB2 + j] = v;
}

// ---- pass 3: 256^2 tile, 8-wave, 4-deep-ring counted-vmcnt pipeline
__global__ __launch_bounds__(512, 2) void band_gemm_8p(
    const uint16_t* __restrict__ xb,
    const uint16_t* __restrict__ wd,
    const float* __restrict__ bias,
    float* __restrict__ out)
{
    __shared__ __align__(128) uint8_t lds[131072];  // 4 ring bufs x 32KB {A:16KB, B:16KB}

    // XCD-aware bijective swizzle (nwg = 512, %8 == 0); by-major per XCD -> x-panel L2 reuse
    const int id  = blockIdx.x;
    const int cpx = gridDim.x >> 3;                 // 64
    const int wg  = (id & 7) * cpx + (id >> 3);
    const int bx  = wg & 15;                        // N tile
    const int by  = wg >> 4;                        // M tile
    const int brow = by * BM;
    const int bcol = bx * BN;

    const int wlo    = bcol - BW;
    const int kstart = wlo > 0 ? wlo : 0;           // multiple of 256
    const int kend   = (bcol + BN + BW) < IN_F ? (bcol + BN + BW) : IN_F;
    const int nt     = (kend - kstart) >> 5;        // 24..40 K-tiles of 32
    const int j0     = kstart - wlo;                // 0 or 512

    const int tid  = threadIdx.x;
    const int w    = tid >> 6;                      // wave 0..7
    const int lane = tid & 63;
    const int ln   = lane & 15;
    const int kc   = lane >> 4;
    const int wm   = w >> 2;                        // 0..1 (M half)
    const int wn   = w & 3;                         // 0..3 (N quarter)

    // staging geometry: thread covers byte tid*16 of each 8KB gload (128 rows x 64B)
    // LDS byte (r,chunk c) stores logical chunk c ^ ((r>>1)&3)  -> pre-swizzled source
    const int srow = tid >> 2;                      // 0..127
    const int scs  = (tid & 3) ^ ((srow >> 1) & 3);
    const uint16_t* sA0 = xb + (size_t)(brow + srow) * IN_F + kstart + scs * 8;
    const uint16_t* sA1 = sA0 + (size_t)128 * IN_F;
    const uint16_t* sB0 = wd + (size_t)(bcol + srow) * WB2 + j0 + scs * 8;
    const uint16_t* sB1 = sB0 + (size_t)128 * WB2;

    // fragment read addressing (same verified swizzle: 0 bank conflicts at 128^2)
    const int swz  = (kc ^ ((ln >> 1) & 3)) << 4;
    const int aoff = ((wm << 7) + ln) << 6;           // (wm*128 + ln)*64 ; frag a adds 1024
    const int boff = 16384 + (((wn << 6) + ln) << 6); // B region ; frag b adds 1024

#define GLOAD(srcp, dst_off)                                                             \
    __builtin_amdgcn_global_load_lds(                                                    \
        (const __attribute__((address_space(1))) uint32_t*)(srcp),                       \
        (__attribute__((address_space(3))) uint32_t*)(lds + (dst_off) + (w << 10)),      \
        16, 0, 0)

    f32x4 acc[8][4] = {};

    // prologue: stage K-tiles 0,1,2 (12 gloads); drain to 8 -> tile 0 resident
    #pragma unroll
    for (int tt = 0; tt < 3; ++tt) {
        GLOAD(sA0 + tt * 32, tt * 32768 + 0);
        GLOAD(sA1 + tt * 32, tt * 32768 + 8192);
        GLOAD(sB0 + tt * 32, tt * 32768 + 16384);
        GLOAD(sB1 + tt * 32, tt * 32768 + 24576);
    }
    asm volatile("s_waitcnt vmcnt(8)" ::: "memory");
    __builtin_amdgcn_s_barrier();

    for (int t = 0; t < nt; ++t) {
        const int cur = (t & 3) << 15;
        const int pr  = ((t + 3) & 3) << 15;            // slot last read at iter t-1
        const int ts  = (t + 3 < nt ? t + 3 : nt - 1) * 32;  // clamp: dead-slot refill

        // ---------- phase 0: read A(8)+B(2) frags, stage next A, MFMA n-half 0
        bf16x8 af[8];
        #pragma unroll
        for (int a = 0; a < 8; ++a)
            af[a] = *(const bf16x8*)(lds + cur + aoff + a * 1024 + swz);
        bf16x8 bf0 = *(const bf16x8*)(lds + cur + boff + 0 * 1024 + swz);
        bf16x8 bf1 = *(const bf16x8*)(lds + cur + boff + 1 * 1024 + swz);
        GLOAD(sA0 + ts, pr + 0);
        GLOAD(sA1 + ts, pr + 8192);
        asm volatile("" ::: "memory");
        __builtin_amdgcn_s_barrier();
        __builtin_amdgcn_s_setprio(1);
        #pragma unroll
        for (int a = 0; a < 8; ++a) {
            acc[a][0] = __builtin_amdgcn_mfma_f32_16x16x32_bf16(af[a], bf0, acc[a][0], 0, 0, 0);
            acc[a][1] = __builtin_amdgcn_mfma_f32_16x16x32_bf16(af[a], bf1, acc[a][1], 0, 0, 0);
        }
        __builtin_amdgcn_s_setprio(0);
        asm volatile("" ::: "memory");
        __builtin_amdgcn_s_barrier();

        // ---------- phase 1: read B(2) frags, stage next B, MFMA n-half 1
        bf16x8 bf2 = *(const bf16x8*)(lds + cur + boff + 2 * 1024 + swz);
        bf16x8 bf3 = *(const bf16x8*)(lds + cur + boff + 3 * 1024 + swz);
        GLOAD(sB0 + ts, pr + 16384);
        GLOAD(sB1 + ts, pr + 24576);
        // counted wait: allow tiles t+2,t+3 (8 loads) in flight; tile t+1 retired
        asm volatile("s_waitcnt vmcnt(8)" ::: "memory");
        __builtin_amdgcn_s_barrier();
        __builtin_amdgcn_s_setprio(1);
        #pragma unroll
        for (int a = 0; a < 8; ++a) {
            acc[a][2] = __builtin_amdgcn_mfma_f32_16x16x32_bf16(af[a], bf2, acc[a][2], 0, 0, 0);
            acc[a][3] = __builtin_amdgcn_mfma_f32_16x16x32_bf16(af[a], bf3, acc[a][3], 0, 0, 0);
        }
        __builtin_amdgcn_s_setprio(0);
        asm volatile("" ::: "memory");
        __builtin_amdgcn_s_barrier();
    }
#undef GLOAD

    asm volatile("s_waitcnt vmcnt(0)" ::: "memory");   // retire dead prefetches

    // epilogue: C/D map col = lane&15, row = (lane>>4)*4 + q
    const int ocol = bcol + (wn << 6) + ln;
    float bsv[4];
    #pragma unroll
    for (int b = 0; b < 4; ++b) bsv[b] = bias[ocol + b * 16];

    #pragma unroll
    for (int a = 0; a < 8; ++a) {
        #pragma unroll
        for (int q = 0; q < 4; ++q) {
            const int row = brow + (wm << 7) + a * 16 + (kc << 2) + q;
            float* po = out + (size_t)row * OUT_F + ocol;
            #pragma unroll
            for (int b = 0; b < 4; ++b)
                po[b * 16] = acc[a][b][q] + bsv[b];
        }
    }
}

// ---- fallback (ws too small / odd M): fp32 tiled kernel, known correct
__global__ __launch_bounds__(256) void band_gemm_f32(
    const float* __restrict__ x, const float* __restrict__ wv,
    const float* __restrict__ bias, float* __restrict__ out, int M)
{
    __shared__ float Xs[128][33];
    __shared__ float Ws[32][130];
    const int tid = threadIdx.x;
    const int tx = tid & 15, ty = tid >> 4;
    const int bcol = blockIdx.x * 128, brow = blockIdx.y * 128;
    const int klo = (bcol >= BW) ? (bcol - BW) : 0;
    const int khi = min(IN_F, bcol + 128 + BW);
    float acc[8][8];
    #pragma unroll
    for (int a = 0; a < 8; ++a)
        #pragma unroll
        for (int b = 0; b < 8; ++b) acc[a][b] = 0.f;
    const int xc4 = (tid & 7) * 4, xr0 = tid >> 3;
    const int wc = tid & 31, wr0 = tid >> 5;
    for (int k0 = klo; k0 < khi; k0 += 32) {
        #pragma unroll
        for (int p = 0; p < 4; ++p) {
            const int r = xr0 + 32 * p;
            const float4 v = *reinterpret_cast<const float4*>(&x[(size_t)(brow + r) * IN_F + (k0 + xc4)]);
            Xs[r][xc4 + 0] = v.x; Xs[r][xc4 + 1] = v.y; Xs[r][xc4 + 2] = v.z; Xs[r][xc4 + 3] = v.w;
        }
        const int i = k0 + wc;
        #pragma unroll
        for (int p = 0; p < 16; ++p) {
            const int r = wr0 + 8 * p;
            const int o = bcol + r;
            const int lo = (o >= BW) ? (o - BW) : 0;
            float v = 0.f;
            if (i >= o - BW && i <= o + BW) v = wv[band_start(o) + (i - lo)];
            Ws[wc][r] = v;
        }
        __syncthreads();
        #pragma unroll
        for (int k = 0; k < 32; ++k) {
            float am[8];
            #pragma unroll
            for (int a = 0; a < 8; ++a) am[a] = Xs[ty * 8 + a][k];
            float bo[8];
            #pragma unroll
            for (int b = 0; b < 4; ++b) { bo[b] = Ws[k][tx * 4 + b]; bo[4 + b] = Ws[k][tx * 4 + 64 + b]; }
            #pragma unroll
            for (int a = 0; a < 8; ++a)
                #pragma unroll
                for (int b = 0; b < 8; ++b) acc[a][b] = fmaf(am[a], bo[b], acc[a][b]);
        }
        __syncthreads();
    }
    #pragma unroll
    for (int a = 0; a < 8; ++a) {
        const size_t row = (size_t)(brow + ty * 8 + a);
        #pragma unroll
        for (int b = 0; b < 4; ++b) {
            out[row * OUT_F + bcol + tx * 4 + b]      = acc[a][b]     + bias[bcol + tx * 4 + b];
            out[row * OUT_F + bcol + tx * 4 + 64 + b] = acc[a][4 + b] + bias[bcol + tx * 4 + 64 + b];
        }
    }
}

extern "C" void kernel_launch(void* const* d_in, const int* in_sizes, int n_in,
                              void* d_out, int out_size, void* d_ws, size_t ws_size,
                              hipStream_t stream) {
    const float* x    = (const float*)d_in[0];
    const float* wv   = (const float*)d_in[1];
    const float* bias = (const float*)d_in[2];
    float* out        = (float*)d_out;

    const int M = in_sizes[0] / IN_F;                         // 8192
    const size_t xb_bytes = (size_t)M * IN_F * 2;             // 64 MB
    const size_t wd_bytes = (size_t)OUT_F * WB2 * 2;          // 10.5 MB

    if (ws_size >= xb_bytes + wd_bytes && (M % BM) == 0) {
        uint16_t* xb  = (uint16_t*)d_ws;
        uint16_t* wdp = (uint16_t*)((uint8_t*)d_ws + xb_bytes);
        cvt_x<<<2048, 256, 0, stream>>>(x, xb, M * IN_F / 4);
        cvt_w<<<dim3(WB2 / 256, OUT_F), 256, 0, stream>>>(wv, wdp);
        band_gemm_8p<<<(M / BM) * (OUT_F / BN), 512, 0, stream>>>(xb, wdp, bias, out);
    } else {
        dim3 grid(OUT_F / 128, M / 128);
        band_gemm_f32<<<grid, 256, 0, stream>>>(x, wv, bias, out, M);
    }
}